// Round 10
// baseline (147.401 us; speedup 1.0000x reference)
//
#include <hip/hip_runtime.h>
#include <hip/hip_cooperative_groups.h>
#include <stdint.h>

namespace cg = cooperative_groups;

#define HW 65536
#define BATCH 64
#define KTOP 200
#define TLOW 16.0f         // candidate pre-filter: P(diff >= 16) ~ 4.6% for 2*chi2(3)
#define TLOW_BITS 0x41800000u
#define NBLK 1024          // 16 blocks per batch
#define NSLOT 128          // candidate slots per WAVE (1024 elems/wave, mean ~47, 12 sigma)
#define SLOTS_PER_B 64     // 16 blocks * 4 waves
#define VPT32 32           // select: 32 reg values/thread x 256 thr = 8192 = 64*128

// ---------------------------------------------------------------------------
// Single cooperative kernel.
// Phase A (1024 blocks): diff + per-wave candidate compaction (no LDS, no
//   atomics; wave-private slot regions, ballot/popcount indexing).
// grid.sync()  — one amortized device-wide barrier w/ memory visibility.
// Phase B (64 selector blocks, blk==0 of each batch): flat register gather
//   of the batch's [64][128] slot array + exact kth-largest binary search
//   on bit patterns + top-KTOP sum, atomicAdd into out.
// ---------------------------------------------------------------------------
__global__ __launch_bounds__(256) void fused_coop(
    const float* __restrict__ pred,
    const float* __restrict__ target,
    float* __restrict__ cand,        // [NBLK*4][NSLOT]
    uint32_t* __restrict__ bcnt,     // [NBLK*4]
    float* __restrict__ out)
{
    __shared__ uint32_t scnt_s[64];
    __shared__ uint32_t meta[2];
    __shared__ uint32_t xa[4];
    __shared__ uint32_t mxw[4];
    __shared__ float    wsumS[4];
    __shared__ uint32_t wcntS[4];

    const int tid  = threadIdx.x;
    const int lane = tid & 63;
    const int wave = tid >> 6;
    const int b    = blockIdx.x >> 4;        // 16 blocks per batch
    const int blk  = blockIdx.x & 15;
    const int slot = blockIdx.x * 4 + wave;  // global wave-slot id

    if (blockIdx.x == 0 && tid == 0) out[0] = 0.0f;

    // ================= phase A: diff + compact =================
    {
        const float4* p = (const float4*)pred;
        const float4* t = (const float4*)target;
        const long bb = (long)b * 49152;     // 3 * 16384 float4 per batch
        float* cs = cand + (long)slot * NSLOT;

        const unsigned long long lmask =
            (lane == 63) ? ~0ull : ((1ull << (lane + 1)) - 1ull);
        uint32_t wcount = 0;

        #pragma unroll
        for (int chunk = 0; chunk < 4; ++chunk) {
            const int pos = blk * 1024 + chunk * 256 + tid;
            long base = bb + pos;
            float4 p0 = p[base], p1 = p[base + 16384], p2 = p[base + 32768];
            float4 t0 = t[base], t1 = t[base + 16384], t2 = t[base + 32768];

            float d[4];
            {
                float a0 = t0.x - p0.x, a1 = t1.x - p1.x, a2 = t2.x - p2.x;
                d[0] = a0 * a0 + a1 * a1 + a2 * a2;
            }
            {
                float a0 = t0.y - p0.y, a1 = t1.y - p1.y, a2 = t2.y - p2.y;
                d[1] = a0 * a0 + a1 * a1 + a2 * a2;
            }
            {
                float a0 = t0.z - p0.z, a1 = t1.z - p1.z, a2 = t2.z - p2.z;
                d[2] = a0 * a0 + a1 * a1 + a2 * a2;
            }
            {
                float a0 = t0.w - p0.w, a1 = t1.w - p1.w, a2 = t2.w - p2.w;
                d[3] = a0 * a0 + a1 * a1 + a2 * a2;
            }

            #pragma unroll
            for (int j = 0; j < 4; ++j) {
                bool pr = d[j] >= TLOW;
                unsigned long long mask = __ballot(pr);
                if (pr) {
                    uint32_t idx = wcount + (uint32_t)__popcll(mask & lmask) - 1u;
                    if (idx < NSLOT) cs[idx] = d[j];
                }
                wcount += (uint32_t)__popcll(mask);   // wave-uniform
            }
        }
        if (lane == 0) bcnt[slot] = wcount;
    }

    // ================= device-wide barrier =================
    cg::this_grid().sync();

    if (blk != 0) return;                    // 64 selector blocks remain

    // ================= phase B: select + sum for batch b =================
    if (tid < 64) {
        uint32_t c = bcnt[b * SLOTS_PER_B + tid];
        scnt_s[tid] = c;
        uint32_t tot = c;
        for (int o = 32; o > 0; o >>= 1) tot += __shfl_xor(tot, o, 64);
        bool anyovf = (__ballot(c > NSLOT) != 0ull);
        if (tid == 0) {
            meta[0] = tot;
            meta[1] = anyovf ? 1u : 0u;
        }
    }
    __syncthreads();

    const uint32_t total = meta[0];
    const bool fb = (meta[1] != 0) || (total < KTOP);

    const float* pb = pred   + (long)b * 3 * HW;
    const float* tb = target + (long)b * 3 * HW;

    if (!fb) {
        // ---- flat unconditional gather: 8 coalesced float4/thread ----
        const float4* c4 = (const float4*)(cand + (long)b * SLOTS_PER_B * NSLOT);
        const int s0 = tid >> 5;
        const int k  = (tid & 31) * 4;
        uint32_t u[VPT32];
        #pragma unroll
        for (int j = 0; j < 8; ++j) {
            float4 v = c4[j * 256 + tid];
            uint32_t cs = scnt_s[j * 8 + s0];
            u[j * 4 + 0] = (uint32_t)(k + 0) < cs ? __float_as_uint(v.x) : 0u;
            u[j * 4 + 1] = (uint32_t)(k + 1) < cs ? __float_as_uint(v.y) : 0u;
            u[j * 4 + 2] = (uint32_t)(k + 2) < cs ? __float_as_uint(v.z) : 0u;
            u[j * 4 + 3] = (uint32_t)(k + 3) < cs ? __float_as_uint(v.w) : 0u;
        }

        // ---- block max ----
        uint32_t mx = 0;
        #pragma unroll
        for (int j = 0; j < VPT32; ++j) mx = u[j] > mx ? u[j] : mx;
        for (int o = 32; o > 0; o >>= 1) {
            uint32_t m2 = __shfl_xor(mx, o, 64);
            mx = m2 > mx ? m2 : mx;
        }
        if (lane == 0) mxw[wave] = mx;
        __syncthreads();
        mx = mxw[0];
        #pragma unroll
        for (int w = 1; w < 4; ++w) mx = mxw[w] > mx ? mxw[w] : mx;

        // ---- binary search: exact kth-largest bit pattern ----
        uint32_t lo = TLOW_BITS, hi = mx + 1;
        while (hi - lo > 1) {
            uint32_t mid = lo + ((hi - lo) >> 1);
            uint32_t cnt = 0;
            #pragma unroll
            for (int j = 0; j < VPT32; ++j) cnt += (u[j] >= mid) ? 1u : 0u;
            for (int o = 32; o > 0; o >>= 1) cnt += __shfl_xor(cnt, o, 64);
            if (lane == 0) xa[wave] = cnt;
            __syncthreads();
            cnt = xa[0] + xa[1] + xa[2] + xa[3];
            __syncthreads();
            if (cnt >= KTOP) lo = mid; else hi = mid;
        }
        const uint32_t T = lo;

        // ---- top-KTOP sum with tie handling ----
        float    s = 0.0f;
        uint32_t c = 0;
        #pragma unroll
        for (int j = 0; j < VPT32; ++j) {
            if (u[j] > T) { s += __uint_as_float(u[j]); c += 1u; }
        }
        for (int o = 32; o > 0; o >>= 1) {
            s += __shfl_xor(s, o, 64);
            c += __shfl_xor(c, o, 64);
        }
        if (lane == 0) { wsumS[wave] = s; wcntS[wave] = c; }
        __syncthreads();
        if (tid == 0) {
            float    S = 0.0f;
            uint32_t C = 0;
            #pragma unroll
            for (int w = 0; w < 4; ++w) { S += wsumS[w]; C += wcntS[w]; }
            float partial = S + (float)(KTOP - C) * __uint_as_float(T);
            atomicAdd(out, partial * (1.0f / (float)(BATCH * KTOP)));
        }
        return;
    }

    // ---- fallback: exact streaming select over recomputed row ----
    auto getd = [&](uint32_t idx) -> float {
        float a0 = tb[idx] - pb[idx];
        float a1 = tb[HW + idx] - pb[HW + idx];
        float a2 = tb[2 * HW + idx] - pb[2 * HW + idx];
        return a0 * a0 + a1 * a1 + a2 * a2;
    };
    uint32_t mx = 0;
    for (uint32_t i = tid; i < HW; i += 256) {
        uint32_t v = __float_as_uint(getd(i));
        mx = v > mx ? v : mx;
    }
    for (int o = 32; o > 0; o >>= 1) {
        uint32_t m2 = __shfl_xor(mx, o, 64);
        mx = m2 > mx ? m2 : mx;
    }
    if (lane == 0) mxw[wave] = mx;
    __syncthreads();
    mx = mxw[0];
    #pragma unroll
    for (int w = 1; w < 4; ++w) mx = mxw[w] > mx ? mxw[w] : mx;

    uint32_t lo = 0, hi = mx + 1;
    while (hi - lo > 1) {
        uint32_t mid = lo + ((hi - lo) >> 1);
        uint32_t cnt = 0;
        for (uint32_t i = tid; i < HW; i += 256)
            cnt += (__float_as_uint(getd(i)) >= mid) ? 1u : 0u;
        for (int o = 32; o > 0; o >>= 1) cnt += __shfl_xor(cnt, o, 64);
        if (lane == 0) xa[wave] = cnt;
        __syncthreads();
        cnt = xa[0] + xa[1] + xa[2] + xa[3];
        __syncthreads();
        if (cnt >= KTOP) lo = mid; else hi = mid;
    }
    const uint32_t T = lo;
    float    s = 0.0f;
    uint32_t c = 0;
    for (uint32_t i = tid; i < HW; i += 256) {
        uint32_t v = __float_as_uint(getd(i));
        if (v > T) { s += __uint_as_float(v); c += 1u; }
    }
    for (int o = 32; o > 0; o >>= 1) {
        s += __shfl_xor(s, o, 64);
        c += __shfl_xor(c, o, 64);
    }
    if (lane == 0) { wsumS[wave] = s; wcntS[wave] = c; }
    __syncthreads();
    if (tid == 0) {
        float    S = 0.0f;
        uint32_t C = 0;
        #pragma unroll
        for (int w = 0; w < 4; ++w) { S += wsumS[w]; C += wcntS[w]; }
        float partial = S + (float)(KTOP - C) * __uint_as_float(T);
        atomicAdd(out, partial * (1.0f / (float)(BATCH * KTOP)));
    }
}

// ---------------------------------------------------------------------------
// Non-cooperative fallback path (used only if coop launch fails / ws small):
// R9's proven two-kernel pipeline.
// ---------------------------------------------------------------------------
__global__ __launch_bounds__(256) void diff_compact(
    const float* __restrict__ pred,
    const float* __restrict__ target,
    float* __restrict__ cand,
    uint32_t* __restrict__ bcnt,
    float* __restrict__ out)
{
    const int tid  = threadIdx.x;
    const int lane = tid & 63;
    const int wave = tid >> 6;
    const int b    = blockIdx.x >> 4;
    const int blk  = blockIdx.x & 15;
    const int slot = blockIdx.x * 4 + wave;

    if (blockIdx.x == 0 && tid == 0) out[0] = 0.0f;

    const float4* p = (const float4*)pred;
    const float4* t = (const float4*)target;
    const long bb = (long)b * 49152;
    float* cs = cand + (long)slot * NSLOT;

    const unsigned long long lmask = (lane == 63) ? ~0ull : ((1ull << (lane + 1)) - 1ull);
    uint32_t wcount = 0;

    #pragma unroll
    for (int chunk = 0; chunk < 4; ++chunk) {
        const int pos = blk * 1024 + chunk * 256 + tid;
        long base = bb + pos;
        float4 p0 = p[base], p1 = p[base + 16384], p2 = p[base + 32768];
        float4 t0 = t[base], t1 = t[base + 16384], t2 = t[base + 32768];

        float d[4];
        { float a0=t0.x-p0.x, a1=t1.x-p1.x, a2=t2.x-p2.x; d[0]=a0*a0+a1*a1+a2*a2; }
        { float a0=t0.y-p0.y, a1=t1.y-p1.y, a2=t2.y-p2.y; d[1]=a0*a0+a1*a1+a2*a2; }
        { float a0=t0.z-p0.z, a1=t1.z-p1.z, a2=t2.z-p2.z; d[2]=a0*a0+a1*a1+a2*a2; }
        { float a0=t0.w-p0.w, a1=t1.w-p1.w, a2=t2.w-p2.w; d[3]=a0*a0+a1*a1+a2*a2; }

        #pragma unroll
        for (int j = 0; j < 4; ++j) {
            bool pr = d[j] >= TLOW;
            unsigned long long mask = __ballot(pr);
            if (pr) {
                uint32_t idx = wcount + (uint32_t)__popcll(mask & lmask) - 1u;
                if (idx < NSLOT) cs[idx] = d[j];
            }
            wcount += (uint32_t)__popcll(mask);
        }
    }
    if (lane == 0) bcnt[slot] = wcount;
}

__global__ __launch_bounds__(256) void select_sum(
    const float* __restrict__ cand,      // null -> always fallback
    const uint32_t* __restrict__ bcnt,
    const float* __restrict__ pred,
    const float* __restrict__ target,
    float* __restrict__ out)
{
    __shared__ uint32_t scnt_s[64];
    __shared__ uint32_t meta[2];
    __shared__ uint32_t xa[4];
    __shared__ uint32_t mxw[4];
    __shared__ float    wsumS[4];
    __shared__ uint32_t wcntS[4];

    const int b    = blockIdx.x;
    const int tid  = threadIdx.x;
    const int lane = tid & 63;
    const int wave = tid >> 6;

    if (tid < 64) {
        uint32_t c = cand ? bcnt[b * SLOTS_PER_B + tid] : 0u;
        scnt_s[tid] = c;
        uint32_t tot = c;
        for (int o = 32; o > 0; o >>= 1) tot += __shfl_xor(tot, o, 64);
        bool anyovf = (__ballot(c > NSLOT) != 0ull);
        if (tid == 0) {
            meta[0] = tot;
            meta[1] = (cand && !anyovf) ? 0u : 1u;
        }
    }
    __syncthreads();

    const uint32_t total = meta[0];
    const bool fb = (meta[1] != 0) || (total < KTOP);

    const float* pb = pred   + (long)b * 3 * HW;
    const float* tb = target + (long)b * 3 * HW;

    if (!fb) {
        const float4* c4 = (const float4*)(cand + (long)b * SLOTS_PER_B * NSLOT);
        const int s0 = tid >> 5;
        const int k  = (tid & 31) * 4;
        uint32_t u[VPT32];
        #pragma unroll
        for (int j = 0; j < 8; ++j) {
            float4 v = c4[j * 256 + tid];
            uint32_t cs = scnt_s[j * 8 + s0];
            u[j * 4 + 0] = (uint32_t)(k + 0) < cs ? __float_as_uint(v.x) : 0u;
            u[j * 4 + 1] = (uint32_t)(k + 1) < cs ? __float_as_uint(v.y) : 0u;
            u[j * 4 + 2] = (uint32_t)(k + 2) < cs ? __float_as_uint(v.z) : 0u;
            u[j * 4 + 3] = (uint32_t)(k + 3) < cs ? __float_as_uint(v.w) : 0u;
        }

        uint32_t mx = 0;
        #pragma unroll
        for (int j = 0; j < VPT32; ++j) mx = u[j] > mx ? u[j] : mx;
        for (int o = 32; o > 0; o >>= 1) {
            uint32_t m2 = __shfl_xor(mx, o, 64);
            mx = m2 > mx ? m2 : mx;
        }
        if (lane == 0) mxw[wave] = mx;
        __syncthreads();
        mx = mxw[0];
        #pragma unroll
        for (int w = 1; w < 4; ++w) mx = mxw[w] > mx ? mxw[w] : mx;

        uint32_t lo = TLOW_BITS, hi = mx + 1;
        while (hi - lo > 1) {
            uint32_t mid = lo + ((hi - lo) >> 1);
            uint32_t cnt = 0;
            #pragma unroll
            for (int j = 0; j < VPT32; ++j) cnt += (u[j] >= mid) ? 1u : 0u;
            for (int o = 32; o > 0; o >>= 1) cnt += __shfl_xor(cnt, o, 64);
            if (lane == 0) xa[wave] = cnt;
            __syncthreads();
            cnt = xa[0] + xa[1] + xa[2] + xa[3];
            __syncthreads();
            if (cnt >= KTOP) lo = mid; else hi = mid;
        }
        const uint32_t T = lo;

        float    s = 0.0f;
        uint32_t c = 0;
        #pragma unroll
        for (int j = 0; j < VPT32; ++j) {
            if (u[j] > T) { s += __uint_as_float(u[j]); c += 1u; }
        }
        for (int o = 32; o > 0; o >>= 1) {
            s += __shfl_xor(s, o, 64);
            c += __shfl_xor(c, o, 64);
        }
        if (lane == 0) { wsumS[wave] = s; wcntS[wave] = c; }
        __syncthreads();
        if (tid == 0) {
            float    S = 0.0f;
            uint32_t C = 0;
            #pragma unroll
            for (int w = 0; w < 4; ++w) { S += wsumS[w]; C += wcntS[w]; }
            float partial = S + (float)(KTOP - C) * __uint_as_float(T);
            atomicAdd(out, partial * (1.0f / (float)(BATCH * KTOP)));
        }
        return;
    }

    auto getd = [&](uint32_t idx) -> float {
        float a0 = tb[idx] - pb[idx];
        float a1 = tb[HW + idx] - pb[HW + idx];
        float a2 = tb[2 * HW + idx] - pb[2 * HW + idx];
        return a0 * a0 + a1 * a1 + a2 * a2;
    };
    uint32_t mx = 0;
    for (uint32_t i = tid; i < HW; i += 256) {
        uint32_t v = __float_as_uint(getd(i));
        mx = v > mx ? v : mx;
    }
    for (int o = 32; o > 0; o >>= 1) {
        uint32_t m2 = __shfl_xor(mx, o, 64);
        mx = m2 > mx ? m2 : mx;
    }
    if (lane == 0) mxw[wave] = mx;
    __syncthreads();
    mx = mxw[0];
    #pragma unroll
    for (int w = 1; w < 4; ++w) mx = mxw[w] > mx ? mxw[w] : mx;

    uint32_t lo = 0, hi = mx + 1;
    while (hi - lo > 1) {
        uint32_t mid = lo + ((hi - lo) >> 1);
        uint32_t cnt = 0;
        for (uint32_t i = tid; i < HW; i += 256)
            cnt += (__float_as_uint(getd(i)) >= mid) ? 1u : 0u;
        for (int o = 32; o > 0; o >>= 1) cnt += __shfl_xor(cnt, o, 64);
        if (lane == 0) xa[wave] = cnt;
        __syncthreads();
        cnt = xa[0] + xa[1] + xa[2] + xa[3];
        __syncthreads();
        if (cnt >= KTOP) lo = mid; else hi = mid;
    }
    const uint32_t T = lo;
    float    s = 0.0f;
    uint32_t c = 0;
    for (uint32_t i = tid; i < HW; i += 256) {
        uint32_t v = __float_as_uint(getd(i));
        if (v > T) { s += __uint_as_float(v); c += 1u; }
    }
    for (int o = 32; o > 0; o >>= 1) {
        s += __shfl_xor(s, o, 64);
        c += __shfl_xor(c, o, 64);
    }
    if (lane == 0) { wsumS[wave] = s; wcntS[wave] = c; }
    __syncthreads();
    if (tid == 0) {
        float    S = 0.0f;
        uint32_t C = 0;
        #pragma unroll
        for (int w = 0; w < 4; ++w) { S += wsumS[w]; C += wcntS[w]; }
        float partial = S + (float)(KTOP - C) * __uint_as_float(T);
        atomicAdd(out, partial * (1.0f / (float)(BATCH * KTOP)));
    }
}

__global__ void zero_out(float* __restrict__ out) { out[0] = 0.0f; }

extern "C" void kernel_launch(void* const* d_in, const int* in_sizes, int n_in,
                              void* d_out, int out_size, void* d_ws, size_t ws_size,
                              hipStream_t stream)
{
    const float* pred   = (const float*)d_in[0];
    const float* target = (const float*)d_in[1];
    float* out = (float*)d_out;

    const int nslots = NBLK * 4;                            // 4096
    uint32_t* bcnt = (uint32_t*)d_ws;                       // 16 KB
    float*    cand = (float*)((char*)d_ws + nslots * 4);    // 2 MB
    const size_t need = (size_t)nslots * 4 + (size_t)nslots * NSLOT * 4;

    if (ws_size >= need) {
        void* args[] = {(void*)&pred, (void*)&target, (void*)&cand,
                        (void*)&bcnt, (void*)&out};
        hipError_t e = hipLaunchCooperativeKernel(
            (const void*)fused_coop, dim3(NBLK), dim3(256), args, 0, stream);
        if (e != hipSuccess) {
            // non-cooperative fallback: proven two-kernel pipeline
            diff_compact<<<NBLK, 256, 0, stream>>>(pred, target, cand, bcnt, out);
            select_sum<<<BATCH, 256, 0, stream>>>(cand, bcnt, pred, target, out);
        }
    } else {
        zero_out<<<1, 1, 0, stream>>>(out);
        select_sum<<<BATCH, 256, 0, stream>>>(nullptr, nullptr, pred, target, out);
    }
}

// Round 11
// 67.390 us; speedup vs baseline: 2.1873x; 2.1873x over previous
//
#include <hip/hip_runtime.h>
#include <stdint.h>

#define HW 65536
#define BATCH 64
#define KTOP 200
#define TLOW 16.0f         // candidate pre-filter: P(diff >= 16) ~ 4.6% for 2*chi2(3)
#define TLOW_BITS 0x41800000u
#define WSLOT 512          // per-wave candidate slots (wave covers 4096 elems, mean ~190, 24 sigma)
#define NW 16              // waves per block

__device__ float g_partials[BATCH];

// ---------------------------------------------------------------------------
// One block per batch (1024 threads). Phase 1: stream the batch's 1.57 MB,
// per-wave ballot-compact candidates (diff >= TLOW) into private LDS regions.
// Phase 2: load 8 values/thread into registers, 16-ary exact bit-pattern
// bracket search (ballot/popcount counting, 3 barriers/round, ~6 rounds),
// then top-KTOP sum with tie handling. Plain-store partial to device global.
// Fallback (overflow / starved, never on this data): exact streaming search.
// ---------------------------------------------------------------------------
__global__ __launch_bounds__(1024) void batch_topk(
    const float* __restrict__ pred,
    const float* __restrict__ target)
{
    __shared__ float    cbuf[NW * WSLOT];      // 32 KB
    __shared__ uint32_t wcnt_s[NW];
    __shared__ uint32_t cntmat[NW * 15];
    __shared__ uint32_t cnts_s[15];
    __shared__ uint32_t meta[3];               // {total, ovf, max}
    __shared__ uint32_t bc[2];
    __shared__ uint32_t mxs[NW];
    __shared__ float    wsum_s[NW];
    __shared__ uint32_t wcnt2_s[NW];

    const int b    = blockIdx.x;
    const int tid  = threadIdx.x;
    const int lane = tid & 63;
    const int wave = tid >> 6;

    // ================= phase 1: stream + compact =================
    const float4* p4 = (const float4*)pred   + (long)b * 49152;
    const float4* t4 = (const float4*)target + (long)b * 49152;
    float* my = cbuf + wave * WSLOT;
    const unsigned long long lmask =
        (lane == 63) ? ~0ull : ((1ull << (lane + 1)) - 1ull);
    uint32_t wcount = 0;

    for (int c = 0; c < 16; ++c) {
        const int i = (c << 10) + tid;         // float4 index in batch plane
        float4 p0 = p4[i], p1 = p4[i + 16384], p2 = p4[i + 32768];
        float4 t0 = t4[i], t1 = t4[i + 16384], t2 = t4[i + 32768];
        float d[4];
        { float a0=t0.x-p0.x, a1=t1.x-p1.x, a2=t2.x-p2.x; d[0]=a0*a0+a1*a1+a2*a2; }
        { float a0=t0.y-p0.y, a1=t1.y-p1.y, a2=t2.y-p2.y; d[1]=a0*a0+a1*a1+a2*a2; }
        { float a0=t0.z-p0.z, a1=t1.z-p1.z, a2=t2.z-p2.z; d[2]=a0*a0+a1*a1+a2*a2; }
        { float a0=t0.w-p0.w, a1=t1.w-p1.w, a2=t2.w-p2.w; d[3]=a0*a0+a1*a1+a2*a2; }
        #pragma unroll
        for (int j = 0; j < 4; ++j) {
            bool pr = d[j] >= TLOW;
            unsigned long long mask = __ballot(pr);
            if (pr) {
                uint32_t idx = wcount + (uint32_t)__popcll(mask & lmask) - 1u;
                if (idx < WSLOT) my[idx] = d[j];
            }
            wcount += (uint32_t)__popcll(mask);  // wave-uniform
        }
    }
    if (lane == 0) wcnt_s[wave] = wcount;
    __syncthreads();

    // ================= registers: 8 values/thread + max =================
    uint32_t u[8];
    uint32_t mx = 0;
    #pragma unroll
    for (int k = 0; k < 8; ++k) {
        int slot = (k << 10) + tid;            // 0..8191
        int reg  = slot >> 9;                  // /WSLOT
        int off  = slot & (WSLOT - 1);
        uint32_t v = __float_as_uint(cbuf[slot]);
        v = ((uint32_t)off < wcnt_s[reg]) ? v : 0u;   // masked pad (deterministic)
        u[k] = v;
        mx = v > mx ? v : mx;
    }
    for (int o = 32; o > 0; o >>= 1) {
        uint32_t m2 = __shfl_xor(mx, o, 64);
        mx = m2 > mx ? m2 : mx;
    }
    if (lane == 0) mxs[wave] = mx;
    __syncthreads();
    if (tid == 0) {
        uint32_t tot = 0, ov = 0, m = 0;
        #pragma unroll
        for (int w = 0; w < NW; ++w) {
            uint32_t cc = wcnt_s[w];
            tot += cc;
            ov |= (cc > WSLOT) ? 1u : 0u;
            m = mxs[w] > m ? mxs[w] : m;
        }
        meta[0] = tot; meta[1] = ov; meta[2] = m;
    }
    __syncthreads();

    const uint32_t total = meta[0];
    const bool fb = (meta[1] != 0) || (total < KTOP);

    if (!fb) {
        // ============ 16-ary exact bracket search on bit patterns ============
        // invariant: count(>=lo) >= KTOP, count(>=hi) < KTOP
        uint32_t lo = TLOW_BITS, hi = meta[2] + 1;
        while (hi - lo > 1) {
            const uint32_t range = hi - lo;
            const uint32_t step  = (range >= 16) ? (range >> 4) : 1u;
            uint32_t cm[15];
            #pragma unroll
            for (int m = 0; m < 15; ++m) cm[m] = 0;
            #pragma unroll
            for (int m = 1; m <= 15; ++m) {
                const uint32_t t = lo + step * (uint32_t)m;
                #pragma unroll
                for (int k = 0; k < 8; ++k)
                    cm[m - 1] += (uint32_t)__popcll(__ballot(u[k] >= t));
            }
            if (lane == 0) {
                #pragma unroll
                for (int m = 0; m < 15; ++m) cntmat[wave * 15 + m] = cm[m];
            }
            __syncthreads();
            if (tid < 15) {
                uint32_t ssum = 0;
                #pragma unroll
                for (int w = 0; w < NW; ++w) ssum += cntmat[w * 15 + tid];
                cnts_s[tid] = ssum;
            }
            __syncthreads();
            if (tid == 0) {
                uint32_t nlo = lo, nhi = lo + step;
                for (int m = 15; m >= 1; --m) {
                    if (cnts_s[m - 1] >= KTOP) {
                        nlo = lo + step * (uint32_t)m;
                        nhi = (m == 15) ? hi : lo + step * (uint32_t)(m + 1);
                        break;
                    }
                }
                if (nhi > hi) nhi = hi;
                bc[0] = nlo; bc[1] = nhi;
            }
            __syncthreads();
            lo = bc[0]; hi = bc[1];
        }
        const uint32_t T = lo;

        // ============ top-KTOP sum with tie handling ============
        float    s = 0.0f;
        uint32_t c = 0;
        #pragma unroll
        for (int k = 0; k < 8; ++k) {
            if (u[k] > T) { s += __uint_as_float(u[k]); c += 1u; }
        }
        for (int o = 32; o > 0; o >>= 1) {
            s += __shfl_xor(s, o, 64);
            c += __shfl_xor(c, o, 64);
        }
        if (lane == 0) { wsum_s[wave] = s; wcnt2_s[wave] = c; }
        __syncthreads();
        if (tid == 0) {
            float    S = 0.0f;
            uint32_t C = 0;
            #pragma unroll
            for (int w = 0; w < NW; ++w) { S += wsum_s[w]; C += wcnt2_s[w]; }
            g_partials[b] = S + (float)(KTOP - C) * __uint_as_float(T);
        }
        return;
    }

    // ============ fallback: exact streaming search (never on this data) =====
    const float* pb = pred   + (long)b * 3 * HW;
    const float* tb = target + (long)b * 3 * HW;
    auto getd = [&](uint32_t idx) -> float {
        float a0 = tb[idx] - pb[idx];
        float a1 = tb[HW + idx] - pb[HW + idx];
        float a2 = tb[2 * HW + idx] - pb[2 * HW + idx];
        return a0 * a0 + a1 * a1 + a2 * a2;
    };
    uint32_t mxl = 0;
    for (uint32_t i = tid; i < HW; i += 1024) {
        uint32_t v = __float_as_uint(getd(i));
        mxl = v > mxl ? v : mxl;
    }
    for (int o = 32; o > 0; o >>= 1) {
        uint32_t m2 = __shfl_xor(mxl, o, 64);
        mxl = m2 > mxl ? m2 : mxl;
    }
    if (lane == 0) mxs[wave] = mxl;
    __syncthreads();
    if (tid == 0) {
        uint32_t m = 0;
        #pragma unroll
        for (int w = 0; w < NW; ++w) m = mxs[w] > m ? mxs[w] : m;
        bc[0] = m;
    }
    __syncthreads();
    uint32_t lo = 0, hi = bc[0] + 1;
    __syncthreads();
    while (hi - lo > 1) {
        uint32_t mid = lo + ((hi - lo) >> 1);
        uint32_t cl = 0;
        for (uint32_t i = tid; i < HW; i += 1024)
            cl += (__float_as_uint(getd(i)) >= mid) ? 1u : 0u;
        for (int o = 32; o > 0; o >>= 1) cl += __shfl_xor(cl, o, 64);
        if (lane == 0) cntmat[wave] = cl;
        __syncthreads();
        if (tid == 0) {
            uint32_t cnt = 0;
            #pragma unroll
            for (int w = 0; w < NW; ++w) cnt += cntmat[w];
            bc[0] = cnt;
        }
        __syncthreads();
        if (bc[0] >= KTOP) lo = mid; else hi = mid;
        __syncthreads();
    }
    const uint32_t T = lo;
    float    s = 0.0f;
    uint32_t c = 0;
    for (uint32_t i = tid; i < HW; i += 1024) {
        uint32_t v = __float_as_uint(getd(i));
        if (v > T) { s += __uint_as_float(v); c += 1u; }
    }
    for (int o = 32; o > 0; o >>= 1) {
        s += __shfl_xor(s, o, 64);
        c += __shfl_xor(c, o, 64);
    }
    if (lane == 0) { wsum_s[wave] = s; wcnt2_s[wave] = c; }
    __syncthreads();
    if (tid == 0) {
        float    S = 0.0f;
        uint32_t C = 0;
        #pragma unroll
        for (int w = 0; w < NW; ++w) { S += wsum_s[w]; C += wcnt2_s[w]; }
        g_partials[b] = S + (float)(KTOP - C) * __uint_as_float(T);
    }
}

// ---------------------------------------------------------------------------
// Finalize: mean of 64 per-batch top-k sums -> scalar
// ---------------------------------------------------------------------------
__global__ void finalize_kernel(float* __restrict__ out)
{
    float v = g_partials[threadIdx.x];
    for (int off = 32; off > 0; off >>= 1)
        v += __shfl_down(v, off, 64);
    if (threadIdx.x == 0)
        out[0] = v / (float)(BATCH * KTOP);
}

extern "C" void kernel_launch(void* const* d_in, const int* in_sizes, int n_in,
                              void* d_out, int out_size, void* d_ws, size_t ws_size,
                              hipStream_t stream)
{
    const float* pred   = (const float*)d_in[0];
    const float* target = (const float*)d_in[1];
    float* out = (float*)d_out;

    batch_topk<<<BATCH, 1024, 0, stream>>>(pred, target);
    finalize_kernel<<<1, 64, 0, stream>>>(out);
}

// Round 12
// 37.921 us; speedup vs baseline: 3.8871x; 1.7771x over previous
//
#include <hip/hip_runtime.h>
#include <stdint.h>

#define HW 65536
#define BATCH 64
#define KTOP 200
#define TLOW 16.0f         // candidate pre-filter: P(diff >= 16) ~ 4.6% for 2*chi2(3)
#define TLOW_BITS 0x41800000u
#define NBLK 1024          // 16 blocks per batch
#define NSLOT 128          // candidate slots per WAVE (1024 elems/wave, mean ~47, 12 sigma)
#define SLOTS_PER_B 64     // 16 blocks * 4 waves
#define VPT32 32           // select: 32 reg values/thread x 256 thr = 8192 = 64*128

// ---------------------------------------------------------------------------
// Kernel 1: diff + per-wave candidate compaction, PHASE-SPLIT for MLP:
// phase L issues all 24 float4 loads + FMA reduction (no cross-lane ops in
// between -> loads stay in flight); phase C does the 16 ballot/compact steps.
// d[4][4] is fully-unrolled static-index (registers, no scratch).
// ---------------------------------------------------------------------------
__global__ __launch_bounds__(256) void diff_compact(
    const float* __restrict__ pred,
    const float* __restrict__ target,
    float* __restrict__ cand,        // [NBLK*4][NSLOT]
    uint32_t* __restrict__ bcnt,     // [NBLK*4]
    float* __restrict__ out)
{
    const int tid  = threadIdx.x;
    const int lane = tid & 63;
    const int wave = tid >> 6;
    const int b    = blockIdx.x >> 4;        // 16 blocks per batch
    const int blk  = blockIdx.x & 15;
    const int slot = blockIdx.x * 4 + wave;  // global wave-slot id

    if (blockIdx.x == 0 && tid == 0) out[0] = 0.0f;   // K2 accumulates into out

    const float4* p4 = (const float4*)pred   + (long)b * 49152;
    const float4* t4 = (const float4*)target + (long)b * 49152;
    float* cs = cand + (long)slot * NSLOT;

    // ---------------- phase L: all loads + FMA (no cross-lane ops) ----------
    float d[4][4];
    #pragma unroll
    for (int c = 0; c < 4; ++c) {
        const int i = blk * 1024 + c * 256 + tid;     // float4 index in batch
        float4 p0 = p4[i], p1 = p4[i + 16384], p2 = p4[i + 32768];
        float4 t0 = t4[i], t1 = t4[i + 16384], t2 = t4[i + 32768];
        {
            float a0 = t0.x - p0.x, a1 = t1.x - p1.x, a2 = t2.x - p2.x;
            d[c][0] = a0 * a0 + a1 * a1 + a2 * a2;
        }
        {
            float a0 = t0.y - p0.y, a1 = t1.y - p1.y, a2 = t2.y - p2.y;
            d[c][1] = a0 * a0 + a1 * a1 + a2 * a2;
        }
        {
            float a0 = t0.z - p0.z, a1 = t1.z - p1.z, a2 = t2.z - p2.z;
            d[c][2] = a0 * a0 + a1 * a1 + a2 * a2;
        }
        {
            float a0 = t0.w - p0.w, a1 = t1.w - p1.w, a2 = t2.w - p2.w;
            d[c][3] = a0 * a0 + a1 * a1 + a2 * a2;
        }
    }

    // ---------------- phase C: ballot compaction ----------------------------
    const unsigned long long lmask =
        (lane == 63) ? ~0ull : ((1ull << (lane + 1)) - 1ull);
    uint32_t wcount = 0;
    #pragma unroll
    for (int c = 0; c < 4; ++c) {
        #pragma unroll
        for (int j = 0; j < 4; ++j) {
            bool pr = d[c][j] >= TLOW;
            unsigned long long mask = __ballot(pr);
            if (pr) {
                uint32_t idx = wcount + (uint32_t)__popcll(mask & lmask) - 1u;
                if (idx < NSLOT) cs[idx] = d[c][j];
            }
            wcount += (uint32_t)__popcll(mask);   // wave-uniform
        }
    }
    if (lane == 0) bcnt[slot] = wcount;           // raw count; >NSLOT -> K2 fallback
}

// ---------------------------------------------------------------------------
// Kernel 2 (verbatim R9): one block (256 thr) per batch. Flat register gather
// of the [64][128] slot array, exact kth-largest bit-pattern binary search,
// top-KTOP sum with tie handling. Fallback: streaming over recomputed row.
// ---------------------------------------------------------------------------
__global__ __launch_bounds__(256) void select_sum(
    const float* __restrict__ cand,      // null -> fallback for all batches
    const uint32_t* __restrict__ bcnt,
    const float* __restrict__ pred,
    const float* __restrict__ target,
    float* __restrict__ out)
{
    __shared__ uint32_t scnt_s[64];
    __shared__ uint32_t meta[2];
    __shared__ uint32_t xa[4];
    __shared__ uint32_t mxw[4];
    __shared__ float    wsumS[4];
    __shared__ uint32_t wcntS[4];

    const int b    = blockIdx.x;
    const int tid  = threadIdx.x;
    const int lane = tid & 63;
    const int wave = tid >> 6;

    if (tid < 64) {
        uint32_t c = cand ? bcnt[b * SLOTS_PER_B + tid] : 0u;
        scnt_s[tid] = c;
        uint32_t tot = c;
        for (int o = 32; o > 0; o >>= 1) tot += __shfl_xor(tot, o, 64);
        bool anyovf = (__ballot(c > NSLOT) != 0ull);
        if (tid == 0) {
            meta[0] = tot;
            meta[1] = (cand && !anyovf) ? 0u : 1u;
        }
    }
    __syncthreads();

    const uint32_t total = meta[0];
    const bool fb = (meta[1] != 0) || (total < KTOP);

    const float* pb = pred   + (long)b * 3 * HW;
    const float* tb = target + (long)b * 3 * HW;

    if (!fb) {
        const float4* c4 = (const float4*)(cand + (long)b * SLOTS_PER_B * NSLOT);
        const int s0 = tid >> 5;
        const int k  = (tid & 31) * 4;
        uint32_t u[VPT32];
        #pragma unroll
        for (int j = 0; j < 8; ++j) {
            float4 v = c4[j * 256 + tid];
            uint32_t cs = scnt_s[j * 8 + s0];
            u[j * 4 + 0] = (uint32_t)(k + 0) < cs ? __float_as_uint(v.x) : 0u;
            u[j * 4 + 1] = (uint32_t)(k + 1) < cs ? __float_as_uint(v.y) : 0u;
            u[j * 4 + 2] = (uint32_t)(k + 2) < cs ? __float_as_uint(v.z) : 0u;
            u[j * 4 + 3] = (uint32_t)(k + 3) < cs ? __float_as_uint(v.w) : 0u;
        }

        uint32_t mx = 0;
        #pragma unroll
        for (int j = 0; j < VPT32; ++j) mx = u[j] > mx ? u[j] : mx;
        for (int o = 32; o > 0; o >>= 1) {
            uint32_t m2 = __shfl_xor(mx, o, 64);
            mx = m2 > mx ? m2 : mx;
        }
        if (lane == 0) mxw[wave] = mx;
        __syncthreads();
        mx = mxw[0];
        #pragma unroll
        for (int w = 1; w < 4; ++w) mx = mxw[w] > mx ? mxw[w] : mx;

        uint32_t lo = TLOW_BITS, hi = mx + 1;
        while (hi - lo > 1) {
            uint32_t mid = lo + ((hi - lo) >> 1);
            uint32_t cnt = 0;
            #pragma unroll
            for (int j = 0; j < VPT32; ++j) cnt += (u[j] >= mid) ? 1u : 0u;
            for (int o = 32; o > 0; o >>= 1) cnt += __shfl_xor(cnt, o, 64);
            if (lane == 0) xa[wave] = cnt;
            __syncthreads();
            cnt = xa[0] + xa[1] + xa[2] + xa[3];
            __syncthreads();
            if (cnt >= KTOP) lo = mid; else hi = mid;
        }
        const uint32_t T = lo;

        float    s = 0.0f;
        uint32_t c = 0;
        #pragma unroll
        for (int j = 0; j < VPT32; ++j) {
            if (u[j] > T) { s += __uint_as_float(u[j]); c += 1u; }
        }
        for (int o = 32; o > 0; o >>= 1) {
            s += __shfl_xor(s, o, 64);
            c += __shfl_xor(c, o, 64);
        }
        if (lane == 0) { wsumS[wave] = s; wcntS[wave] = c; }
        __syncthreads();
        if (tid == 0) {
            float    S = 0.0f;
            uint32_t C = 0;
            #pragma unroll
            for (int w = 0; w < 4; ++w) { S += wsumS[w]; C += wcntS[w]; }
            float partial = S + (float)(KTOP - C) * __uint_as_float(T);
            atomicAdd(out, partial * (1.0f / (float)(BATCH * KTOP)));
        }
        return;
    }

    auto getd = [&](uint32_t idx) -> float {
        float a0 = tb[idx] - pb[idx];
        float a1 = tb[HW + idx] - pb[HW + idx];
        float a2 = tb[2 * HW + idx] - pb[2 * HW + idx];
        return a0 * a0 + a1 * a1 + a2 * a2;
    };
    uint32_t mx = 0;
    for (uint32_t i = tid; i < HW; i += 256) {
        uint32_t v = __float_as_uint(getd(i));
        mx = v > mx ? v : mx;
    }
    for (int o = 32; o > 0; o >>= 1) {
        uint32_t m2 = __shfl_xor(mx, o, 64);
        mx = m2 > mx ? m2 : mx;
    }
    if (lane == 0) mxw[wave] = mx;
    __syncthreads();
    mx = mxw[0];
    #pragma unroll
    for (int w = 1; w < 4; ++w) mx = mxw[w] > mx ? mxw[w] : mx;

    uint32_t lo = 0, hi = mx + 1;
    while (hi - lo > 1) {
        uint32_t mid = lo + ((hi - lo) >> 1);
        uint32_t cnt = 0;
        for (uint32_t i = tid; i < HW; i += 256)
            cnt += (__float_as_uint(getd(i)) >= mid) ? 1u : 0u;
        for (int o = 32; o > 0; o >>= 1) cnt += __shfl_xor(cnt, o, 64);
        if (lane == 0) xa[wave] = cnt;
        __syncthreads();
        cnt = xa[0] + xa[1] + xa[2] + xa[3];
        __syncthreads();
        if (cnt >= KTOP) lo = mid; else hi = mid;
    }
    const uint32_t T = lo;
    float    s = 0.0f;
    uint32_t c = 0;
    for (uint32_t i = tid; i < HW; i += 256) {
        uint32_t v = __float_as_uint(getd(i));
        if (v > T) { s += __uint_as_float(v); c += 1u; }
    }
    for (int o = 32; o > 0; o >>= 1) {
        s += __shfl_xor(s, o, 64);
        c += __shfl_xor(c, o, 64);
    }
    if (lane == 0) { wsumS[wave] = s; wcntS[wave] = c; }
    __syncthreads();
    if (tid == 0) {
        float    S = 0.0f;
        uint32_t C = 0;
        #pragma unroll
        for (int w = 0; w < 4; ++w) { S += wsumS[w]; C += wcntS[w]; }
        float partial = S + (float)(KTOP - C) * __uint_as_float(T);
        atomicAdd(out, partial * (1.0f / (float)(BATCH * KTOP)));
    }
}

// tiny init for the ws-too-small path (select_sum fallback needs out=0)
__global__ void zero_out(float* __restrict__ out) { out[0] = 0.0f; }

extern "C" void kernel_launch(void* const* d_in, const int* in_sizes, int n_in,
                              void* d_out, int out_size, void* d_ws, size_t ws_size,
                              hipStream_t stream)
{
    const float* pred   = (const float*)d_in[0];
    const float* target = (const float*)d_in[1];
    float* out = (float*)d_out;

    const int nslots = NBLK * 4;                            // 4096
    uint32_t* bcnt = (uint32_t*)d_ws;                       // 16 KB
    float*    cand = (float*)((char*)d_ws + nslots * 4);    // 2 MB
    const size_t need = (size_t)nslots * 4 + (size_t)nslots * NSLOT * 4;

    if (ws_size >= need) {
        diff_compact<<<NBLK, 256, 0, stream>>>(pred, target, cand, bcnt, out);
        select_sum<<<BATCH, 256, 0, stream>>>(cand, bcnt, pred, target, out);
    } else {
        zero_out<<<1, 1, 0, stream>>>(out);
        select_sum<<<BATCH, 256, 0, stream>>>(nullptr, nullptr, pred, target, out);
    }
}

// Round 13
// 33.845 us; speedup vs baseline: 4.3552x; 1.1204x over previous
//
#include <hip/hip_runtime.h>
#include <stdint.h>

#define HW 65536
#define BATCH 64
#define KTOP 200
#define TLOW 26.0f          // P(2*chi2_3 >= 26) ~ 0.0046 -> ~302 cands/batch; T200 ~ 27.4
#define TLOW_BITS 0x41D00000u
#define NBLK 4096           // 64 blocks per batch, 1024 elems per block
#define NSLOT 32            // per-BLOCK candidate slots (mean ~4.8, Poisson tail ~1e-17)
#define BLKS_PER_B 64

// ---------------------------------------------------------------------------
// Kernel 1: diff + block-level candidate compaction.
// 4096 blocks x 256 thr, 1 float4-position/thread (6 loads ~40 VGPR);
// __launch_bounds__(256,8) -> VGPR<=64 -> 8 blocks/CU = 32 waves/CU (MLP).
// Ballot per wave + LDS-atomic base + fixed 32-slot global region per block.
// ---------------------------------------------------------------------------
__global__ __launch_bounds__(256, 8) void diff_compact(
    const float* __restrict__ pred,
    const float* __restrict__ target,
    float* __restrict__ cand,        // [NBLK][NSLOT]
    uint32_t* __restrict__ bcnt,     // [NBLK]
    float* __restrict__ out)
{
    __shared__ float    sbuf[NSLOT];
    __shared__ uint32_t scnt;

    const int tid  = threadIdx.x;
    const int lane = tid & 63;
    const int b    = blockIdx.x >> 6;        // 64 blocks per batch
    const int blk  = blockIdx.x & 63;

    if (blockIdx.x == 0 && tid == 0) out[0] = 0.0f;   // K2 accumulates into out
    if (tid == 0) scnt = 0;
    __syncthreads();

    const float4* p4 = (const float4*)pred   + (long)b * 49152;
    const float4* t4 = (const float4*)target + (long)b * 49152;

    // ---- 6 loads (all issued before use), diff ----
    const int i = blk * 256 + tid;           // float4 index in batch plane
    float4 p0 = p4[i], p1 = p4[i + 16384], p2 = p4[i + 32768];
    float4 t0 = t4[i], t1 = t4[i + 16384], t2 = t4[i + 32768];
    float d[4];
    { float a0=t0.x-p0.x, a1=t1.x-p1.x, a2=t2.x-p2.x; d[0]=a0*a0+a1*a1+a2*a2; }
    { float a0=t0.y-p0.y, a1=t1.y-p1.y, a2=t2.y-p2.y; d[1]=a0*a0+a1*a1+a2*a2; }
    { float a0=t0.z-p0.z, a1=t1.z-p1.z, a2=t2.z-p2.z; d[2]=a0*a0+a1*a1+a2*a2; }
    { float a0=t0.w-p0.w, a1=t1.w-p1.w, a2=t2.w-p2.w; d[3]=a0*a0+a1*a1+a2*a2; }

    // ---- ballot compact into LDS (block-level) ----
    const unsigned long long lmask =
        (lane == 63) ? ~0ull : ((1ull << (lane + 1)) - 1ull);
    #pragma unroll
    for (int j = 0; j < 4; ++j) {
        bool pr = d[j] >= TLOW;
        unsigned long long mask = __ballot(pr);
        if (mask) {                                    // wave-uniform
            uint32_t c = (uint32_t)__popcll(mask);
            uint32_t wb = 0;
            if (lane == 0) wb = atomicAdd(&scnt, c);   // LDS atomic (on-CU)
            wb = __shfl(wb, 0, 64);
            if (pr) {
                uint32_t idx = wb + (uint32_t)__popcll(mask & lmask) - 1u;
                if (idx < NSLOT) sbuf[idx] = d[j];
            }
        }
    }
    __syncthreads();

    const uint32_t n = scnt;
    if (tid == 0) bcnt[blockIdx.x] = n;                // raw; >NSLOT -> K2 fallback
    if (tid < NSLOT && tid < n)
        cand[(long)blockIdx.x * NSLOT + tid] = sbuf[tid];
}

// ---------------------------------------------------------------------------
// Kernel 2: ONE WAVE per batch (64 blocks x 64 thr). Counts live one-per-lane
// (64 blocks/batch); flat masked gather of the [64][32] region into u[32]
// registers (static indices); exact kth-largest bit-pattern binary search —
// pure register + shfl, ZERO barriers. Fallback: streaming recompute (exact).
// ---------------------------------------------------------------------------
__global__ __launch_bounds__(64, 1) void select_sum(
    const float* __restrict__ cand,      // null -> fallback for all batches
    const uint32_t* __restrict__ bcnt,
    const float* __restrict__ pred,
    const float* __restrict__ target,
    float* __restrict__ out)
{
    const int b    = blockIdx.x;
    const int lane = threadIdx.x;

    // ---- per-block counts: one per lane ----
    uint32_t myc = cand ? bcnt[b * BLKS_PER_B + lane] : 0u;
    const bool ovf = (__ballot(myc > NSLOT) != 0ull);
    uint32_t total = myc;
    for (int o = 32; o > 0; o >>= 1) total += __shfl_xor(total, o, 64);

    const bool fb = (!cand) || ovf || (total < KTOP);

    const float* pb = pred   + (long)b * 3 * HW;
    const float* tb = target + (long)b * 3 * HW;

    if (!fb) {
        // ---- flat masked gather: 8 coalesced float4/lane -> u[32] ----
        const float4* c4 = (const float4*)(cand + (long)b * BLKS_PER_B * NSLOT);
        uint32_t u[32];
        #pragma unroll
        for (int j = 0; j < 8; ++j) {
            float4 v = c4[j * 64 + lane];                  // 512 float4 region
            int slot = j * 8 + (lane >> 3);                // 8 float4 per 32-f slot
            uint32_t cs = __shfl(myc, slot, 64);           // count from owning lane
            uint32_t k  = (lane & 7) * 4;                  // float offset in slot
            u[j * 4 + 0] = (k + 0 < cs) ? __float_as_uint(v.x) : 0u;
            u[j * 4 + 1] = (k + 1 < cs) ? __float_as_uint(v.y) : 0u;
            u[j * 4 + 2] = (k + 2 < cs) ? __float_as_uint(v.z) : 0u;
            u[j * 4 + 3] = (k + 3 < cs) ? __float_as_uint(v.w) : 0u;
        }

        // ---- wave max ----
        uint32_t mx = 0;
        #pragma unroll
        for (int j = 0; j < 32; ++j) mx = u[j] > mx ? u[j] : mx;
        for (int o = 32; o > 0; o >>= 1) {
            uint32_t m2 = __shfl_xor(mx, o, 64);
            mx = m2 > mx ? m2 : mx;
        }

        // ---- binary search: exact kth-largest bit pattern (no barriers) ----
        uint32_t lo = TLOW_BITS, hi = mx + 1;
        while (hi - lo > 1) {
            uint32_t mid = lo + ((hi - lo) >> 1);
            uint32_t cnt = 0;
            #pragma unroll
            for (int j = 0; j < 32; ++j) cnt += (u[j] >= mid) ? 1u : 0u;
            for (int o = 32; o > 0; o >>= 1) cnt += __shfl_xor(cnt, o, 64);
            if (cnt >= KTOP) lo = mid; else hi = mid;      // wave-uniform
        }
        const uint32_t T = lo;

        // ---- top-KTOP sum with tie handling ----
        float    s = 0.0f;
        uint32_t c = 0;
        #pragma unroll
        for (int j = 0; j < 32; ++j) {
            if (u[j] > T) { s += __uint_as_float(u[j]); c += 1u; }
        }
        for (int o = 32; o > 0; o >>= 1) {
            s += __shfl_xor(s, o, 64);
            c += __shfl_xor(c, o, 64);
        }
        if (lane == 0) {
            float partial = s + (float)(KTOP - c) * __uint_as_float(T);
            atomicAdd(out, partial * (1.0f / (float)(BATCH * KTOP)));
        }
        return;
    }

    // ---- fallback: exact streaming search over recomputed row (never hot) --
    auto getd = [&](uint32_t idx) -> float {
        float a0 = tb[idx] - pb[idx];
        float a1 = tb[HW + idx] - pb[HW + idx];
        float a2 = tb[2 * HW + idx] - pb[2 * HW + idx];
        return a0 * a0 + a1 * a1 + a2 * a2;
    };
    uint32_t mx = 0;
    for (uint32_t i = lane; i < HW; i += 64) {
        uint32_t v = __float_as_uint(getd(i));
        mx = v > mx ? v : mx;
    }
    for (int o = 32; o > 0; o >>= 1) {
        uint32_t m2 = __shfl_xor(mx, o, 64);
        mx = m2 > mx ? m2 : mx;
    }
    uint32_t lo = 0, hi = mx + 1;
    while (hi - lo > 1) {
        uint32_t mid = lo + ((hi - lo) >> 1);
        uint32_t cnt = 0;
        for (uint32_t i = lane; i < HW; i += 64)
            cnt += (__float_as_uint(getd(i)) >= mid) ? 1u : 0u;
        for (int o = 32; o > 0; o >>= 1) cnt += __shfl_xor(cnt, o, 64);
        if (cnt >= KTOP) lo = mid; else hi = mid;
    }
    const uint32_t T = lo;
    float    s = 0.0f;
    uint32_t c = 0;
    for (uint32_t i = lane; i < HW; i += 64) {
        uint32_t v = __float_as_uint(getd(i));
        if (v > T) { s += __uint_as_float(v); c += 1u; }
    }
    for (int o = 32; o > 0; o >>= 1) {
        s += __shfl_xor(s, o, 64);
        c += __shfl_xor(c, o, 64);
    }
    if (lane == 0) {
        float partial = s + (float)(KTOP - c) * __uint_as_float(T);
        atomicAdd(out, partial * (1.0f / (float)(BATCH * KTOP)));
    }
}

// tiny init for the ws-too-small path (select_sum fallback needs out=0)
__global__ void zero_out(float* __restrict__ out) { out[0] = 0.0f; }

extern "C" void kernel_launch(void* const* d_in, const int* in_sizes, int n_in,
                              void* d_out, int out_size, void* d_ws, size_t ws_size,
                              hipStream_t stream)
{
    const float* pred   = (const float*)d_in[0];
    const float* target = (const float*)d_in[1];
    float* out = (float*)d_out;

    uint32_t* bcnt = (uint32_t*)d_ws;                       // 16 KB
    float*    cand = (float*)((char*)d_ws + NBLK * 4);      // 512 KB
    const size_t need = (size_t)NBLK * 4 + (size_t)NBLK * NSLOT * 4;

    if (ws_size >= need) {
        diff_compact<<<NBLK, 256, 0, stream>>>(pred, target, cand, bcnt, out);
        select_sum<<<BATCH, 64, 0, stream>>>(cand, bcnt, pred, target, out);
    } else {
        zero_out<<<1, 1, 0, stream>>>(out);
        select_sum<<<BATCH, 64, 0, stream>>>(nullptr, nullptr, pred, target, out);
    }
}

// Round 14
// 33.746 us; speedup vs baseline: 4.3679x; 1.0029x over previous
//
#include <hip/hip_runtime.h>
#include <stdint.h>

#define HW 65536
#define BATCH 64
#define KTOP 200
#define TLOW 26.0f          // P(2*chi2_3 >= 26) ~ 0.0046 -> ~302 cands/batch; T200 ~ 27.4
#define TLOW_BITS 0x41D00000u
#define NBLK 1024           // 16 blocks per batch; wave covers 1024 pixels
#define NSLOT 32            // per-WAVE candidate slots (mean ~4.7, P(>32) ~ 4e-17)
#define SLOTS_PER_B 64      // 16 blocks * 4 waves
#define VPT32 32            // K2: 32 reg values/lane x 64 lanes = 2048 = 64*32

// ---------------------------------------------------------------------------
// Kernel 1: diff + per-wave candidate compaction (R9 structure, retuned).
// No LDS, no barriers, no atomics: each wave owns a private 32-slot global
// region; running count via wave-uniform ballot/popcount. 4 chunks x 6 loads.
// __launch_bounds__(256,8) -> 8 blocks/CU = 32 waves/CU for MLP.
// ---------------------------------------------------------------------------
__global__ __launch_bounds__(256, 8) void diff_compact(
    const float* __restrict__ pred,
    const float* __restrict__ target,
    float* __restrict__ cand,        // [NBLK*4][NSLOT]
    uint32_t* __restrict__ bcnt,     // [NBLK*4]
    float* __restrict__ out)
{
    const int tid  = threadIdx.x;
    const int lane = tid & 63;
    const int wave = tid >> 6;
    const int b    = blockIdx.x >> 4;        // 16 blocks per batch
    const int blk  = blockIdx.x & 15;
    const int slot = blockIdx.x * 4 + wave;  // global wave-slot id

    if (blockIdx.x == 0 && tid == 0) out[0] = 0.0f;   // K2 accumulates into out

    const float4* p4 = (const float4*)pred   + (long)b * 49152;
    const float4* t4 = (const float4*)target + (long)b * 49152;
    float* cs = cand + (long)slot * NSLOT;

    const unsigned long long lmask =
        (lane == 63) ? ~0ull : ((1ull << (lane + 1)) - 1ull);
    uint32_t wcount = 0;

    #pragma unroll
    for (int chunk = 0; chunk < 4; ++chunk) {
        const int i = blk * 1024 + chunk * 256 + tid;  // float4 index in batch
        float4 p0 = p4[i], p1 = p4[i + 16384], p2 = p4[i + 32768];
        float4 t0 = t4[i], t1 = t4[i + 16384], t2 = t4[i + 32768];

        float d[4];
        { float a0=t0.x-p0.x, a1=t1.x-p1.x, a2=t2.x-p2.x; d[0]=a0*a0+a1*a1+a2*a2; }
        { float a0=t0.y-p0.y, a1=t1.y-p1.y, a2=t2.y-p2.y; d[1]=a0*a0+a1*a1+a2*a2; }
        { float a0=t0.z-p0.z, a1=t1.z-p1.z, a2=t2.z-p2.z; d[2]=a0*a0+a1*a1+a2*a2; }
        { float a0=t0.w-p0.w, a1=t1.w-p1.w, a2=t2.w-p2.w; d[3]=a0*a0+a1*a1+a2*a2; }

        #pragma unroll
        for (int j = 0; j < 4; ++j) {
            bool pr = d[j] >= TLOW;
            unsigned long long mask = __ballot(pr);
            if (pr) {
                uint32_t idx = wcount + (uint32_t)__popcll(mask & lmask) - 1u;
                if (idx < NSLOT) cs[idx] = d[j];
            }
            wcount += (uint32_t)__popcll(mask);   // wave-uniform
        }
    }
    if (lane == 0) bcnt[slot] = wcount;           // raw; >NSLOT -> K2 fallback
}

// ---------------------------------------------------------------------------
// Kernel 2 (verbatim R13): ONE WAVE per batch. Counts one-per-lane, flat
// masked gather of the [64][32] region into u[32] registers (static indices),
// exact kth-largest bit-pattern binary search — pure register + shfl, ZERO
// barriers. Fallback: exact streaming recompute.
// ---------------------------------------------------------------------------
__global__ __launch_bounds__(64, 1) void select_sum(
    const float* __restrict__ cand,      // null -> fallback for all batches
    const uint32_t* __restrict__ bcnt,
    const float* __restrict__ pred,
    const float* __restrict__ target,
    float* __restrict__ out)
{
    const int b    = blockIdx.x;
    const int lane = threadIdx.x;

    // ---- per-slot counts: one per lane ----
    uint32_t myc = cand ? bcnt[b * SLOTS_PER_B + lane] : 0u;
    const bool ovf = (__ballot(myc > NSLOT) != 0ull);
    uint32_t total = myc;
    for (int o = 32; o > 0; o >>= 1) total += __shfl_xor(total, o, 64);

    const bool fb = (!cand) || ovf || (total < KTOP);

    const float* pb = pred   + (long)b * 3 * HW;
    const float* tb = target + (long)b * 3 * HW;

    if (!fb) {
        // ---- flat masked gather: 8 coalesced float4/lane -> u[32] ----
        const float4* c4 = (const float4*)(cand + (long)b * SLOTS_PER_B * NSLOT);
        uint32_t u[VPT32];
        #pragma unroll
        for (int j = 0; j < 8; ++j) {
            float4 v = c4[j * 64 + lane];                  // 512 float4 region
            int sl  = j * 8 + (lane >> 3);                 // 8 float4 per 32-f slot
            uint32_t cs = __shfl(myc, sl, 64);             // count from owning lane
            uint32_t k  = (lane & 7) * 4;                  // float offset in slot
            u[j * 4 + 0] = (k + 0 < cs) ? __float_as_uint(v.x) : 0u;
            u[j * 4 + 1] = (k + 1 < cs) ? __float_as_uint(v.y) : 0u;
            u[j * 4 + 2] = (k + 2 < cs) ? __float_as_uint(v.z) : 0u;
            u[j * 4 + 3] = (k + 3 < cs) ? __float_as_uint(v.w) : 0u;
        }

        // ---- wave max ----
        uint32_t mx = 0;
        #pragma unroll
        for (int j = 0; j < VPT32; ++j) mx = u[j] > mx ? u[j] : mx;
        for (int o = 32; o > 0; o >>= 1) {
            uint32_t m2 = __shfl_xor(mx, o, 64);
            mx = m2 > mx ? m2 : mx;
        }

        // ---- binary search: exact kth-largest bit pattern (no barriers) ----
        uint32_t lo = TLOW_BITS, hi = mx + 1;
        while (hi - lo > 1) {
            uint32_t mid = lo + ((hi - lo) >> 1);
            uint32_t cnt = 0;
            #pragma unroll
            for (int j = 0; j < VPT32; ++j) cnt += (u[j] >= mid) ? 1u : 0u;
            for (int o = 32; o > 0; o >>= 1) cnt += __shfl_xor(cnt, o, 64);
            if (cnt >= KTOP) lo = mid; else hi = mid;      // wave-uniform
        }
        const uint32_t T = lo;

        // ---- top-KTOP sum with tie handling ----
        float    s = 0.0f;
        uint32_t c = 0;
        #pragma unroll
        for (int j = 0; j < VPT32; ++j) {
            if (u[j] > T) { s += __uint_as_float(u[j]); c += 1u; }
        }
        for (int o = 32; o > 0; o >>= 1) {
            s += __shfl_xor(s, o, 64);
            c += __shfl_xor(c, o, 64);
        }
        if (lane == 0) {
            float partial = s + (float)(KTOP - c) * __uint_as_float(T);
            atomicAdd(out, partial * (1.0f / (float)(BATCH * KTOP)));
        }
        return;
    }

    // ---- fallback: exact streaming search over recomputed row (never hot) --
    auto getd = [&](uint32_t idx) -> float {
        float a0 = tb[idx] - pb[idx];
        float a1 = tb[HW + idx] - pb[HW + idx];
        float a2 = tb[2 * HW + idx] - pb[2 * HW + idx];
        return a0 * a0 + a1 * a1 + a2 * a2;
    };
    uint32_t mx = 0;
    for (uint32_t i = lane; i < HW; i += 64) {
        uint32_t v = __float_as_uint(getd(i));
        mx = v > mx ? v : mx;
    }
    for (int o = 32; o > 0; o >>= 1) {
        uint32_t m2 = __shfl_xor(mx, o, 64);
        mx = m2 > mx ? m2 : mx;
    }
    uint32_t lo = 0, hi = mx + 1;
    while (hi - lo > 1) {
        uint32_t mid = lo + ((hi - lo) >> 1);
        uint32_t cnt = 0;
        for (uint32_t i = lane; i < HW; i += 64)
            cnt += (__float_as_uint(getd(i)) >= mid) ? 1u : 0u;
        for (int o = 32; o > 0; o >>= 1) cnt += __shfl_xor(cnt, o, 64);
        if (cnt >= KTOP) lo = mid; else hi = mid;
    }
    const uint32_t T = lo;
    float    s = 0.0f;
    uint32_t c = 0;
    for (uint32_t i = lane; i < HW; i += 64) {
        uint32_t v = __float_as_uint(getd(i));
        if (v > T) { s += __uint_as_float(v); c += 1u; }
    }
    for (int o = 32; o > 0; o >>= 1) {
        s += __shfl_xor(s, o, 64);
        c += __shfl_xor(c, o, 64);
    }
    if (lane == 0) {
        float partial = s + (float)(KTOP - c) * __uint_as_float(T);
        atomicAdd(out, partial * (1.0f / (float)(BATCH * KTOP)));
    }
}

// tiny init for the ws-too-small path (select_sum fallback needs out=0)
__global__ void zero_out(float* __restrict__ out) { out[0] = 0.0f; }

extern "C" void kernel_launch(void* const* d_in, const int* in_sizes, int n_in,
                              void* d_out, int out_size, void* d_ws, size_t ws_size,
                              hipStream_t stream)
{
    const float* pred   = (const float*)d_in[0];
    const float* target = (const float*)d_in[1];
    float* out = (float*)d_out;

    const int nslots = NBLK * 4;                            // 4096
    uint32_t* bcnt = (uint32_t*)d_ws;                       // 16 KB
    float*    cand = (float*)((char*)d_ws + nslots * 4);    // 512 KB
    const size_t need = (size_t)nslots * 4 + (size_t)nslots * NSLOT * 4;

    if (ws_size >= need) {
        diff_compact<<<NBLK, 256, 0, stream>>>(pred, target, cand, bcnt, out);
        select_sum<<<BATCH, 64, 0, stream>>>(cand, bcnt, pred, target, out);
    } else {
        zero_out<<<1, 1, 0, stream>>>(out);
        select_sum<<<BATCH, 64, 0, stream>>>(nullptr, nullptr, pred, target, out);
    }
}

// Round 15
// 32.062 us; speedup vs baseline: 4.5974x; 1.0525x over previous
//
#include <hip/hip_runtime.h>
#include <stdint.h>

#define HW 65536
#define BATCH 64
#define KTOP 200
#define TLOW 26.0f          // P(2*chi2_3 >= 26) ~ 0.0046 -> ~302 cands/batch; T200 ~ 27.4
#define TLOW_BITS 0x41D00000u
#define NBLK 1024           // 16 blocks per batch; wave covers 1024 pixels
#define NSLOT 32            // per-WAVE candidate slots (mean ~4.7, P(>32) ~ 4e-17)
#define SLOTS_PER_B 64      // 16 blocks * 4 waves
#define VPT32 32            // K2: 32 reg values/lane x 64 lanes = 2048 = 64*32

typedef float __attribute__((ext_vector_type(4))) f4;

// ---------------------------------------------------------------------------
// Kernel 1: diff + per-wave candidate compaction (R14 structure, verbatim
// except: NONTEMPORAL loads). Stream is read-once -> nt loads skip L2
// allocation, avoiding 100MB of eviction/writeback churn through 4MB L2s.
// ---------------------------------------------------------------------------
__global__ __launch_bounds__(256, 8) void diff_compact(
    const float* __restrict__ pred,
    const float* __restrict__ target,
    float* __restrict__ cand,        // [NBLK*4][NSLOT]
    uint32_t* __restrict__ bcnt,     // [NBLK*4]
    float* __restrict__ out)
{
    const int tid  = threadIdx.x;
    const int lane = tid & 63;
    const int wave = tid >> 6;
    const int b    = blockIdx.x >> 4;        // 16 blocks per batch
    const int blk  = blockIdx.x & 15;
    const int slot = blockIdx.x * 4 + wave;  // global wave-slot id

    if (blockIdx.x == 0 && tid == 0) out[0] = 0.0f;   // K2 accumulates into out

    const f4* p4 = (const f4*)pred   + (long)b * 49152;
    const f4* t4 = (const f4*)target + (long)b * 49152;
    float* cs = cand + (long)slot * NSLOT;

    const unsigned long long lmask =
        (lane == 63) ? ~0ull : ((1ull << (lane + 1)) - 1ull);
    uint32_t wcount = 0;

    #pragma unroll
    for (int chunk = 0; chunk < 4; ++chunk) {
        const int i = blk * 1024 + chunk * 256 + tid;  // float4 index in batch
        f4 p0 = __builtin_nontemporal_load(p4 + i);
        f4 p1 = __builtin_nontemporal_load(p4 + i + 16384);
        f4 p2 = __builtin_nontemporal_load(p4 + i + 32768);
        f4 t0 = __builtin_nontemporal_load(t4 + i);
        f4 t1 = __builtin_nontemporal_load(t4 + i + 16384);
        f4 t2 = __builtin_nontemporal_load(t4 + i + 32768);

        float d[4];
        { float a0=t0.x-p0.x, a1=t1.x-p1.x, a2=t2.x-p2.x; d[0]=a0*a0+a1*a1+a2*a2; }
        { float a0=t0.y-p0.y, a1=t1.y-p1.y, a2=t2.y-p2.y; d[1]=a0*a0+a1*a1+a2*a2; }
        { float a0=t0.z-p0.z, a1=t1.z-p1.z, a2=t2.z-p2.z; d[2]=a0*a0+a1*a1+a2*a2; }
        { float a0=t0.w-p0.w, a1=t1.w-p1.w, a2=t2.w-p2.w; d[3]=a0*a0+a1*a1+a2*a2; }

        #pragma unroll
        for (int j = 0; j < 4; ++j) {
            bool pr = d[j] >= TLOW;
            unsigned long long mask = __ballot(pr);
            if (pr) {
                uint32_t idx = wcount + (uint32_t)__popcll(mask & lmask) - 1u;
                if (idx < NSLOT) cs[idx] = d[j];
            }
            wcount += (uint32_t)__popcll(mask);   // wave-uniform
        }
    }
    if (lane == 0) bcnt[slot] = wcount;           // raw; >NSLOT -> K2 fallback
}

// ---------------------------------------------------------------------------
// Kernel 2 (verbatim R13/R14): ONE WAVE per batch. Counts one-per-lane, flat
// masked gather of the [64][32] region into u[32] registers (static indices),
// exact kth-largest bit-pattern binary search — pure register + shfl, ZERO
// barriers. Fallback: exact streaming recompute.
// ---------------------------------------------------------------------------
__global__ __launch_bounds__(64, 1) void select_sum(
    const float* __restrict__ cand,      // null -> fallback for all batches
    const uint32_t* __restrict__ bcnt,
    const float* __restrict__ pred,
    const float* __restrict__ target,
    float* __restrict__ out)
{
    const int b    = blockIdx.x;
    const int lane = threadIdx.x;

    // ---- per-slot counts: one per lane ----
    uint32_t myc = cand ? bcnt[b * SLOTS_PER_B + lane] : 0u;
    const bool ovf = (__ballot(myc > NSLOT) != 0ull);
    uint32_t total = myc;
    for (int o = 32; o > 0; o >>= 1) total += __shfl_xor(total, o, 64);

    const bool fb = (!cand) || ovf || (total < KTOP);

    const float* pb = pred   + (long)b * 3 * HW;
    const float* tb = target + (long)b * 3 * HW;

    if (!fb) {
        // ---- flat masked gather: 8 coalesced float4/lane -> u[32] ----
        const float4* c4 = (const float4*)(cand + (long)b * SLOTS_PER_B * NSLOT);
        uint32_t u[VPT32];
        #pragma unroll
        for (int j = 0; j < 8; ++j) {
            float4 v = c4[j * 64 + lane];                  // 512 float4 region
            int sl  = j * 8 + (lane >> 3);                 // 8 float4 per 32-f slot
            uint32_t cs = __shfl(myc, sl, 64);             // count from owning lane
            uint32_t k  = (lane & 7) * 4;                  // float offset in slot
            u[j * 4 + 0] = (k + 0 < cs) ? __float_as_uint(v.x) : 0u;
            u[j * 4 + 1] = (k + 1 < cs) ? __float_as_uint(v.y) : 0u;
            u[j * 4 + 2] = (k + 2 < cs) ? __float_as_uint(v.z) : 0u;
            u[j * 4 + 3] = (k + 3 < cs) ? __float_as_uint(v.w) : 0u;
        }

        // ---- wave max ----
        uint32_t mx = 0;
        #pragma unroll
        for (int j = 0; j < VPT32; ++j) mx = u[j] > mx ? u[j] : mx;
        for (int o = 32; o > 0; o >>= 1) {
            uint32_t m2 = __shfl_xor(mx, o, 64);
            mx = m2 > mx ? m2 : mx;
        }

        // ---- binary search: exact kth-largest bit pattern (no barriers) ----
        uint32_t lo = TLOW_BITS, hi = mx + 1;
        while (hi - lo > 1) {
            uint32_t mid = lo + ((hi - lo) >> 1);
            uint32_t cnt = 0;
            #pragma unroll
            for (int j = 0; j < VPT32; ++j) cnt += (u[j] >= mid) ? 1u : 0u;
            for (int o = 32; o > 0; o >>= 1) cnt += __shfl_xor(cnt, o, 64);
            if (cnt >= KTOP) lo = mid; else hi = mid;      // wave-uniform
        }
        const uint32_t T = lo;

        // ---- top-KTOP sum with tie handling ----
        float    s = 0.0f;
        uint32_t c = 0;
        #pragma unroll
        for (int j = 0; j < VPT32; ++j) {
            if (u[j] > T) { s += __uint_as_float(u[j]); c += 1u; }
        }
        for (int o = 32; o > 0; o >>= 1) {
            s += __shfl_xor(s, o, 64);
            c += __shfl_xor(c, o, 64);
        }
        if (lane == 0) {
            float partial = s + (float)(KTOP - c) * __uint_as_float(T);
            atomicAdd(out, partial * (1.0f / (float)(BATCH * KTOP)));
        }
        return;
    }

    // ---- fallback: exact streaming search over recomputed row (never hot) --
    auto getd = [&](uint32_t idx) -> float {
        float a0 = tb[idx] - pb[idx];
        float a1 = tb[HW + idx] - pb[HW + idx];
        float a2 = tb[2 * HW + idx] - pb[2 * HW + idx];
        return a0 * a0 + a1 * a1 + a2 * a2;
    };
    uint32_t mx = 0;
    for (uint32_t i = lane; i < HW; i += 64) {
        uint32_t v = __float_as_uint(getd(i));
        mx = v > mx ? v : mx;
    }
    for (int o = 32; o > 0; o >>= 1) {
        uint32_t m2 = __shfl_xor(mx, o, 64);
        mx = m2 > mx ? m2 : mx;
    }
    uint32_t lo = 0, hi = mx + 1;
    while (hi - lo > 1) {
        uint32_t mid = lo + ((hi - lo) >> 1);
        uint32_t cnt = 0;
        for (uint32_t i = lane; i < HW; i += 64)
            cnt += (__float_as_uint(getd(i)) >= mid) ? 1u : 0u;
        for (int o = 32; o > 0; o >>= 1) cnt += __shfl_xor(cnt, o, 64);
        if (cnt >= KTOP) lo = mid; else hi = mid;
    }
    const uint32_t T = lo;
    float    s = 0.0f;
    uint32_t c = 0;
    for (uint32_t i = lane; i < HW; i += 64) {
        uint32_t v = __float_as_uint(getd(i));
        if (v > T) { s += __uint_as_float(v); c += 1u; }
    }
    for (int o = 32; o > 0; o >>= 1) {
        s += __shfl_xor(s, o, 64);
        c += __shfl_xor(c, o, 64);
    }
    if (lane == 0) {
        float partial = s + (float)(KTOP - c) * __uint_as_float(T);
        atomicAdd(out, partial * (1.0f / (float)(BATCH * KTOP)));
    }
}

// tiny init for the ws-too-small path (select_sum fallback needs out=0)
__global__ void zero_out(float* __restrict__ out) { out[0] = 0.0f; }

extern "C" void kernel_launch(void* const* d_in, const int* in_sizes, int n_in,
                              void* d_out, int out_size, void* d_ws, size_t ws_size,
                              hipStream_t stream)
{
    const float* pred   = (const float*)d_in[0];
    const float* target = (const float*)d_in[1];
    float* out = (float*)d_out;

    const int nslots = NBLK * 4;                            // 4096
    uint32_t* bcnt = (uint32_t*)d_ws;                       // 16 KB
    float*    cand = (float*)((char*)d_ws + nslots * 4);    // 512 KB
    const size_t need = (size_t)nslots * 4 + (size_t)nslots * NSLOT * 4;

    if (ws_size >= need) {
        diff_compact<<<NBLK, 256, 0, stream>>>(pred, target, cand, bcnt, out);
        select_sum<<<BATCH, 64, 0, stream>>>(cand, bcnt, pred, target, out);
    } else {
        zero_out<<<1, 1, 0, stream>>>(out);
        select_sum<<<BATCH, 64, 0, stream>>>(nullptr, nullptr, pred, target, out);
    }
}

// Round 16
// 31.955 us; speedup vs baseline: 4.6127x; 1.0033x over previous
//
#include <hip/hip_runtime.h>
#include <stdint.h>

#define HW 65536
#define BATCH 64
#define KTOP 200
#define TLOW 26.0f          // P(2*chi2_3 >= 26) ~ 0.0046 -> ~302 cands/batch; T200 ~ 27.4
#define TLOW_BITS 0x41D00000u
#define NBLK 2048           // 32 blocks per batch; 8 blocks/CU = 32 waves/CU resident
#define NSLOT 16            // per-WAVE candidate slots (wave covers 512 px, mean ~2.4)
#define SLOTS_PER_B 128     // 32 blocks * 4 waves
#define VPT32 32            // K2: 32 reg values/lane x 64 lanes = 2048 = 128*16

typedef float __attribute__((ext_vector_type(4))) f4;

// ---------------------------------------------------------------------------
// Kernel 1: diff + per-wave candidate compaction. Wave-private global slots,
// no LDS / atomics / barriers; NT loads (read-once stream, skip L2 churn).
// 2048 blocks x 256 thr, 2 chunks each -> 32 waves/CU co-resident (MLP x2).
// ---------------------------------------------------------------------------
__global__ __launch_bounds__(256, 8) void diff_compact(
    const float* __restrict__ pred,
    const float* __restrict__ target,
    float* __restrict__ cand,        // [NBLK*4][NSLOT]
    uint32_t* __restrict__ bcnt,     // [NBLK*4]
    float* __restrict__ out)
{
    const int tid  = threadIdx.x;
    const int lane = tid & 63;
    const int wave = tid >> 6;
    const int b    = blockIdx.x >> 5;        // 32 blocks per batch
    const int blk  = blockIdx.x & 31;
    const int slot = blockIdx.x * 4 + wave;  // global wave-slot id

    if (blockIdx.x == 0 && tid == 0) out[0] = 0.0f;   // K2 accumulates into out

    const f4* p4 = (const f4*)pred   + (long)b * 49152;
    const f4* t4 = (const f4*)target + (long)b * 49152;
    float* cs = cand + (long)slot * NSLOT;

    const unsigned long long lmask =
        (lane == 63) ? ~0ull : ((1ull << (lane + 1)) - 1ull);
    uint32_t wcount = 0;

    #pragma unroll
    for (int chunk = 0; chunk < 2; ++chunk) {
        const int i = blk * 512 + chunk * 256 + tid;   // float4 index in batch
        f4 p0 = __builtin_nontemporal_load(p4 + i);
        f4 p1 = __builtin_nontemporal_load(p4 + i + 16384);
        f4 p2 = __builtin_nontemporal_load(p4 + i + 32768);
        f4 t0 = __builtin_nontemporal_load(t4 + i);
        f4 t1 = __builtin_nontemporal_load(t4 + i + 16384);
        f4 t2 = __builtin_nontemporal_load(t4 + i + 32768);

        float d[4];
        { float a0=t0.x-p0.x, a1=t1.x-p1.x, a2=t2.x-p2.x; d[0]=a0*a0+a1*a1+a2*a2; }
        { float a0=t0.y-p0.y, a1=t1.y-p1.y, a2=t2.y-p2.y; d[1]=a0*a0+a1*a1+a2*a2; }
        { float a0=t0.z-p0.z, a1=t1.z-p1.z, a2=t2.z-p2.z; d[2]=a0*a0+a1*a1+a2*a2; }
        { float a0=t0.w-p0.w, a1=t1.w-p1.w, a2=t2.w-p2.w; d[3]=a0*a0+a1*a1+a2*a2; }

        #pragma unroll
        for (int j = 0; j < 4; ++j) {
            bool pr = d[j] >= TLOW;
            unsigned long long mask = __ballot(pr);
            if (pr) {
                uint32_t idx = wcount + (uint32_t)__popcll(mask & lmask) - 1u;
                if (idx < NSLOT) cs[idx] = d[j];
            }
            wcount += (uint32_t)__popcll(mask);   // wave-uniform
        }
    }
    if (lane == 0) bcnt[slot] = wcount;           // raw; >NSLOT -> K2 fallback
}

// ---------------------------------------------------------------------------
// Kernel 2: ONE WAVE per batch. 128 slots/batch -> 2 counts per lane; flat
// masked gather of the [128][16] region into u[32] registers (static indices,
// wave-uniform j<4 selector), exact kth-largest bit-pattern binary search —
// pure register + shfl, ZERO barriers. Fallback: exact streaming recompute.
// ---------------------------------------------------------------------------
__global__ __launch_bounds__(64, 1) void select_sum(
    const float* __restrict__ cand,      // null -> fallback for all batches
    const uint32_t* __restrict__ bcnt,
    const float* __restrict__ pred,
    const float* __restrict__ target,
    float* __restrict__ out)
{
    const int b    = blockIdx.x;
    const int lane = threadIdx.x;

    // ---- per-slot counts: two per lane (slots lane and 64+lane) ----
    uint32_t myc0 = cand ? bcnt[b * SLOTS_PER_B + lane]      : 0u;
    uint32_t myc1 = cand ? bcnt[b * SLOTS_PER_B + 64 + lane] : 0u;
    const bool ovf = (__ballot(myc0 > NSLOT) != 0ull) ||
                     (__ballot(myc1 > NSLOT) != 0ull);
    uint32_t total = myc0 + myc1;
    for (int o = 32; o > 0; o >>= 1) total += __shfl_xor(total, o, 64);

    const bool fb = (!cand) || ovf || (total < KTOP);

    const float* pb = pred   + (long)b * 3 * HW;
    const float* tb = target + (long)b * 3 * HW;

    if (!fb) {
        // ---- flat masked gather: 8 coalesced float4/lane -> u[32] ----
        // region = [128 slots][16 floats] = 512 float4; f4 index f = j*64+lane
        // slot s = f>>2 = j*16 + (lane>>2); j<4 -> s<64 (myc0), else myc1.
        const float4* c4 = (const float4*)(cand + (long)b * SLOTS_PER_B * NSLOT);
        uint32_t u[VPT32];
        #pragma unroll
        for (int j = 0; j < 8; ++j) {
            float4 v = c4[j * 64 + lane];
            int sl  = (j & 3) * 16 + (lane >> 2);          // slot mod 64
            uint32_t cs = (j < 4) ? __shfl(myc0, sl, 64)
                                  : __shfl(myc1, sl, 64);  // owning lane's count
            uint32_t k  = (lane & 3) * 4;                  // float offset in slot
            u[j * 4 + 0] = (k + 0 < cs) ? __float_as_uint(v.x) : 0u;
            u[j * 4 + 1] = (k + 1 < cs) ? __float_as_uint(v.y) : 0u;
            u[j * 4 + 2] = (k + 2 < cs) ? __float_as_uint(v.z) : 0u;
            u[j * 4 + 3] = (k + 3 < cs) ? __float_as_uint(v.w) : 0u;
        }

        // ---- wave max ----
        uint32_t mx = 0;
        #pragma unroll
        for (int j = 0; j < VPT32; ++j) mx = u[j] > mx ? u[j] : mx;
        for (int o = 32; o > 0; o >>= 1) {
            uint32_t m2 = __shfl_xor(mx, o, 64);
            mx = m2 > mx ? m2 : mx;
        }

        // ---- binary search: exact kth-largest bit pattern (no barriers) ----
        uint32_t lo = TLOW_BITS, hi = mx + 1;
        while (hi - lo > 1) {
            uint32_t mid = lo + ((hi - lo) >> 1);
            uint32_t cnt = 0;
            #pragma unroll
            for (int j = 0; j < VPT32; ++j) cnt += (u[j] >= mid) ? 1u : 0u;
            for (int o = 32; o > 0; o >>= 1) cnt += __shfl_xor(cnt, o, 64);
            if (cnt >= KTOP) lo = mid; else hi = mid;      // wave-uniform
        }
        const uint32_t T = lo;

        // ---- top-KTOP sum with tie handling ----
        float    s = 0.0f;
        uint32_t c = 0;
        #pragma unroll
        for (int j = 0; j < VPT32; ++j) {
            if (u[j] > T) { s += __uint_as_float(u[j]); c += 1u; }
        }
        for (int o = 32; o > 0; o >>= 1) {
            s += __shfl_xor(s, o, 64);
            c += __shfl_xor(c, o, 64);
        }
        if (lane == 0) {
            float partial = s + (float)(KTOP - c) * __uint_as_float(T);
            atomicAdd(out, partial * (1.0f / (float)(BATCH * KTOP)));
        }
        return;
    }

    // ---- fallback: exact streaming search over recomputed row (never hot) --
    auto getd = [&](uint32_t idx) -> float {
        float a0 = tb[idx] - pb[idx];
        float a1 = tb[HW + idx] - pb[HW + idx];
        float a2 = tb[2 * HW + idx] - pb[2 * HW + idx];
        return a0 * a0 + a1 * a1 + a2 * a2;
    };
    uint32_t mx = 0;
    for (uint32_t i = lane; i < HW; i += 64) {
        uint32_t v = __float_as_uint(getd(i));
        mx = v > mx ? v : mx;
    }
    for (int o = 32; o > 0; o >>= 1) {
        uint32_t m2 = __shfl_xor(mx, o, 64);
        mx = m2 > mx ? m2 : mx;
    }
    uint32_t lo = 0, hi = mx + 1;
    while (hi - lo > 1) {
        uint32_t mid = lo + ((hi - lo) >> 1);
        uint32_t cnt = 0;
        for (uint32_t i = lane; i < HW; i += 64)
            cnt += (__float_as_uint(getd(i)) >= mid) ? 1u : 0u;
        for (int o = 32; o > 0; o >>= 1) cnt += __shfl_xor(cnt, o, 64);
        if (cnt >= KTOP) lo = mid; else hi = mid;
    }
    const uint32_t T = lo;
    float    s = 0.0f;
    uint32_t c = 0;
    for (uint32_t i = lane; i < HW; i += 64) {
        uint32_t v = __float_as_uint(getd(i));
        if (v > T) { s += __uint_as_float(v); c += 1u; }
    }
    for (int o = 32; o > 0; o >>= 1) {
        s += __shfl_xor(s, o, 64);
        c += __shfl_xor(c, o, 64);
    }
    if (lane == 0) {
        float partial = s + (float)(KTOP - c) * __uint_as_float(T);
        atomicAdd(out, partial * (1.0f / (float)(BATCH * KTOP)));
    }
}

// tiny init for the ws-too-small path (select_sum fallback needs out=0)
__global__ void zero_out(float* __restrict__ out) { out[0] = 0.0f; }

extern "C" void kernel_launch(void* const* d_in, const int* in_sizes, int n_in,
                              void* d_out, int out_size, void* d_ws, size_t ws_size,
                              hipStream_t stream)
{
    const float* pred   = (const float*)d_in[0];
    const float* target = (const float*)d_in[1];
    float* out = (float*)d_out;

    const int nslots = NBLK * 4;                            // 8192
    uint32_t* bcnt = (uint32_t*)d_ws;                       // 32 KB
    float*    cand = (float*)((char*)d_ws + nslots * 4);    // 512 KB
    const size_t need = (size_t)nslots * 4 + (size_t)nslots * NSLOT * 4;

    if (ws_size >= need) {
        diff_compact<<<NBLK, 256, 0, stream>>>(pred, target, cand, bcnt, out);
        select_sum<<<BATCH, 64, 0, stream>>>(cand, bcnt, pred, target, out);
    } else {
        zero_out<<<1, 1, 0, stream>>>(out);
        select_sum<<<BATCH, 64, 0, stream>>>(nullptr, nullptr, pred, target, out);
    }
}